// Round 1
// baseline (185.880 us; speedup 1.0000x reference)
//
#include <hip/hip_runtime.h>
#include <hip/hip_bf16.h>

// y[b, c] = (sum_k x[b,k] * W[c % 512, k]) + bias[c]
// Strategy: small GEMM (4096x512x4096) in bf16 MFMA, split-K=8 with partials
// written straight into the 8 column-copies of d_out; combine kernel sums the
// 8 copies in place and adds bias.

typedef __bf16 bf8 __attribute__((ext_vector_type(8)));
typedef float f4 __attribute__((ext_vector_type(4)));
typedef unsigned int uint;

constexpr int M = 4096;
constexpr int K = 4096;
constexpr int NS = 512;          // shared rows = y_small columns
constexpr int OUTF = 4096;       // output columns
constexpr int BM = 128, BN = 128, BK = 32;
constexpr int SK = 8;            // K splits (== OUTF/NS column copies)
constexpr int KS = K / SK;       // 512 per split
constexpr int BKP = BK + 8;      // padded LDS stride in bf16 elems (80 B, 16B-aligned)

#define PERM_HI2(hi, lo) __builtin_amdgcn_perm((hi), (lo), 0x07060302u)

__global__ __launch_bounds__(256, 3)
void gemm_split_kernel(const float* __restrict__ x, const float* __restrict__ w,
                       float* __restrict__ out) {
  __shared__ __align__(16) unsigned short As[BM * BKP];
  __shared__ __align__(16) unsigned short Bs[BN * BKP];

  const int gid = blockIdx.x;          // 1024 blocks
  const int mt = gid & 31;             // 32 M tiles (fastest -> W slab reuse in L2)
  const int nt = (gid >> 5) & 3;       // 4 N tiles
  const int s  = gid >> 7;             // 8 K splits

  const int tid = threadIdx.x;
  const int row2 = tid >> 1;           // 0..127: staging row
  const int kc   = (tid & 1) << 4;     // 0 or 16: staging k-offset (16 floats)

  const float* xA = x + (size_t)(mt * BM + row2) * K + s * KS + kc;
  const float* wB = w + (size_t)(nt * BN + row2) * K + s * KS + kc;

  const int lane = tid & 63;
  const int wv = tid >> 6;
  const int wm = (wv & 1) * 64;        // wave M origin
  const int wn = (wv >> 1) * 64;       // wave N origin
  const int lr = lane & 15;
  const int lq = lane >> 4;

  f4 acc[4][4] = {};

  float4 ga[4], gb[4];
#pragma unroll
  for (int i = 0; i < 4; ++i) {
    ga[i] = *reinterpret_cast<const float4*>(xA + i * 4);
    gb[i] = *reinterpret_cast<const float4*>(wB + i * 4);
  }

  constexpr int NITER = KS / BK;       // 16
  for (int kk = 0; kk < NITER; ++kk) {
    // ---- pack fp32 -> bf16 (truncate via v_perm) and store to LDS ----
    uint4 u0 = __builtin_bit_cast(uint4, ga[0]);
    uint4 u1 = __builtin_bit_cast(uint4, ga[1]);
    uint4 u2 = __builtin_bit_cast(uint4, ga[2]);
    uint4 u3 = __builtin_bit_cast(uint4, ga[3]);
    uint4 pa0, pa1;
    pa0.x = PERM_HI2(u0.y, u0.x); pa0.y = PERM_HI2(u0.w, u0.z);
    pa0.z = PERM_HI2(u1.y, u1.x); pa0.w = PERM_HI2(u1.w, u1.z);
    pa1.x = PERM_HI2(u2.y, u2.x); pa1.y = PERM_HI2(u2.w, u2.z);
    pa1.z = PERM_HI2(u3.y, u3.x); pa1.w = PERM_HI2(u3.w, u3.z);
    *reinterpret_cast<uint4*>(&As[row2 * BKP + kc])     = pa0;
    *reinterpret_cast<uint4*>(&As[row2 * BKP + kc + 8]) = pa1;

    uint4 v0 = __builtin_bit_cast(uint4, gb[0]);
    uint4 v1 = __builtin_bit_cast(uint4, gb[1]);
    uint4 v2 = __builtin_bit_cast(uint4, gb[2]);
    uint4 v3 = __builtin_bit_cast(uint4, gb[3]);
    uint4 pb0, pb1;
    pb0.x = PERM_HI2(v0.y, v0.x); pb0.y = PERM_HI2(v0.w, v0.z);
    pb0.z = PERM_HI2(v1.y, v1.x); pb0.w = PERM_HI2(v1.w, v1.z);
    pb1.x = PERM_HI2(v2.y, v2.x); pb1.y = PERM_HI2(v2.w, v2.z);
    pb1.z = PERM_HI2(v3.y, v3.x); pb1.w = PERM_HI2(v3.w, v3.z);
    *reinterpret_cast<uint4*>(&Bs[row2 * BKP + kc])     = pb0;
    *reinterpret_cast<uint4*>(&Bs[row2 * BKP + kc + 8]) = pb1;

    __syncthreads();

    // ---- prefetch next global tile (latency hidden behind MFMA) ----
    if (kk + 1 < NITER) {
      const float* xn = xA + (kk + 1) * BK;
      const float* wn2 = wB + (kk + 1) * BK;
#pragma unroll
      for (int i = 0; i < 4; ++i) {
        ga[i] = *reinterpret_cast<const float4*>(xn + i * 4);
        gb[i] = *reinterpret_cast<const float4*>(wn2 + i * 4);
      }
    }

    // ---- fragment loads + MFMA ----
    bf8 af[4], bfv[4];
#pragma unroll
    for (int mf = 0; mf < 4; ++mf)
      af[mf] = *reinterpret_cast<const bf8*>(&As[(wm + mf * 16 + lr) * BKP + lq * 8]);
#pragma unroll
    for (int nf = 0; nf < 4; ++nf)
      bfv[nf] = *reinterpret_cast<const bf8*>(&Bs[(wn + nf * 16 + lr) * BKP + lq * 8]);

#pragma unroll
    for (int mf = 0; mf < 4; ++mf)
#pragma unroll
      for (int nf = 0; nf < 4; ++nf)
        acc[mf][nf] = __builtin_amdgcn_mfma_f32_16x16x32_bf16(af[mf], bfv[nf], acc[mf][nf], 0, 0, 0);

    __syncthreads();
  }

  // ---- epilogue: write partial into column-copy s of d_out ----
  float* ob = out + (size_t)(mt * BM) * OUTF + s * NS + nt * BN;
#pragma unroll
  for (int mf = 0; mf < 4; ++mf) {
#pragma unroll
    for (int nf = 0; nf < 4; ++nf) {
#pragma unroll
      for (int r = 0; r < 4; ++r) {
        const int row = wm + mf * 16 + lq * 4 + r;
        const int col = wn + nf * 16 + lr;
        ob[(size_t)row * OUTF + col] = acc[mf][nf][r];
      }
    }
  }
}

// Sum the 8 K-split partials (stored in the 8 column copies) in place, add bias.
__global__ __launch_bounds__(256)
void combine_kernel(float* __restrict__ out, const float* __restrict__ bias) {
  const int t = blockIdx.x * 256 + threadIdx.x;   // 524288 threads
  const int b  = t >> 7;                          // row 0..4095
  const int rc = t & 127;                         // float4 index within 512-col copy
  float4* row = reinterpret_cast<float4*>(out) + (size_t)b * (OUTF / 4);
  const float4* bias4 = reinterpret_cast<const float4*>(bias);

  float4 p[8];
#pragma unroll
  for (int s2 = 0; s2 < 8; ++s2) p[s2] = row[s2 * 128 + rc];

  float sx = 0.f, sy = 0.f, sz = 0.f, sw = 0.f;
#pragma unroll
  for (int s2 = 0; s2 < 8; ++s2) {
    sx += p[s2].x; sy += p[s2].y; sz += p[s2].z; sw += p[s2].w;
  }

#pragma unroll
  for (int s2 = 0; s2 < 8; ++s2) {
    float4 bb = bias4[s2 * 128 + rc];
    float4 o;
    o.x = sx + bb.x; o.y = sy + bb.y; o.z = sz + bb.z; o.w = sw + bb.w;
    row[s2 * 128 + rc] = o;
  }
}

extern "C" void kernel_launch(void* const* d_in, const int* in_sizes, int n_in,
                              void* d_out, int out_size, void* d_ws, size_t ws_size,
                              hipStream_t stream) {
  (void)in_sizes; (void)n_in; (void)d_ws; (void)ws_size; (void)out_size;
  const float* x    = (const float*)d_in[0];
  const float* w    = (const float*)d_in[1];
  const float* bias = (const float*)d_in[2];
  float* out = (float*)d_out;

  gemm_split_kernel<<<dim3(32 * 4 * SK), dim3(256), 0, stream>>>(x, w, out);
  combine_kernel<<<dim3((M * NS / 4) / 256), dim3(256), 0, stream>>>(out, bias);
}